// Round 5
// baseline (1578.515 us; speedup 1.0000x reference)
//
#include <hip/hip_runtime.h>
#include <hip/hip_bf16.h>

#define NN 50000     // nodes
#define NR 4         // relations
#define NE 160000    // edges per relation
#define HD 128       // hidden dim
#define OD 100       // out dim
#define NQ 8192      // queries
#define NB_SCAN 196  // 196*256 >= NN

typedef __attribute__((ext_vector_type(8))) short bf16x8;
typedef __attribute__((ext_vector_type(4))) float f32x4;
typedef __attribute__((ext_vector_type(4))) int int4v;

static __device__ __forceinline__ unsigned short f2bf(float f) {
    union { float f; unsigned int u; } v; v.f = f;
    unsigned int u = v.u;
    unsigned int r = u + 0x7FFFu + ((u >> 16) & 1u);   // RNE
    return (unsigned short)(r >> 16);
}
static __device__ __forceinline__ float bflo(unsigned int v) {
    union { unsigned int u; float f; } x; x.u = v << 16; return x.f;
}
static __device__ __forceinline__ float bfhi(unsigned int v) {
    union { unsigned int u; float f; } x; x.u = v & 0xffff0000u; return x.f;
}

// ---------------- graph preprocessing ----------------

__global__ void zero_deg_kernel(int* __restrict__ deg) {
    int i = blockIdx.x * 256 + threadIdx.x;
    if (i < NR * NN) deg[i] = 0;
}

__global__ void count_deg_kernel(const int* __restrict__ edge_dst, int* __restrict__ deg) {
    int i = blockIdx.x * 256 + threadIdx.x;
    if (i < NR * NE) {
        int r = i / NE;
        atomicAdd(&deg[r * NN + edge_dst[i]], 1);
    }
}

__global__ __launch_bounds__(256) void scanA_kernel(const int* __restrict__ deg,
                                                    int* __restrict__ excl,
                                                    int* __restrict__ bsum) {
    const int r = blockIdx.x / NB_SCAN;
    const int b = blockIdx.x % NB_SCAN;
    const int tid = threadIdx.x;
    const int idx = b * 256 + tid;
    int v = (idx < NN) ? deg[r * NN + idx] : 0;
    __shared__ int buf[256];
    buf[tid] = v; __syncthreads();
    int sum = v;
    for (int off = 1; off < 256; off <<= 1) {
        int t = (tid >= off) ? buf[tid - off] : 0;
        __syncthreads();
        sum += t; buf[tid] = sum;
        __syncthreads();
    }
    if (idx < NN) excl[r * NN + idx] = sum - v;
    if (tid == 255) bsum[r * NB_SCAN + b] = sum;
}

__global__ __launch_bounds__(256) void scanB_kernel(int* __restrict__ bsum) {
    const int r = blockIdx.x;
    const int tid = threadIdx.x;
    int v = (tid < NB_SCAN) ? bsum[r * NB_SCAN + tid] : 0;
    __shared__ int buf[256];
    buf[tid] = v; __syncthreads();
    int sum = v;
    for (int off = 1; off < 256; off <<= 1) {
        int t = (tid >= off) ? buf[tid - off] : 0;
        __syncthreads();
        sum += t; buf[tid] = sum;
        __syncthreads();
    }
    if (tid < NB_SCAN) bsum[r * NB_SCAN + tid] = sum - v;
}

__global__ __launch_bounds__(256) void scanC_kernel(const int* __restrict__ excl,
                                                    const int* __restrict__ bsum,
                                                    int* __restrict__ row_start,
                                                    int* __restrict__ cursor) {
    const int r = blockIdx.x / NB_SCAN;
    const int b = blockIdx.x % NB_SCAN;
    const int idx = b * 256 + threadIdx.x;
    if (idx < NN) {
        int v = excl[r * NN + idx] + bsum[r * NB_SCAN + b];
        row_start[r * (NN + 1) + idx] = v;
        cursor[r * NN + idx] = v;
    }
    if (b == 0 && threadIdx.x == 0) row_start[r * (NN + 1) + NN] = NE;
}

__global__ void fill_csr_kernel(const int* __restrict__ edge_src,
                                const int* __restrict__ edge_dst,
                                int* __restrict__ cursor, int2* __restrict__ csr_sd) {
    int i = blockIdx.x * 256 + threadIdx.x;
    if (i < NR * NE) {
        int r = i / NE;
        int dst = edge_dst[i];
        int pos = atomicAdd(&cursor[r * NN + dst], 1);
        csr_sd[r * NE + pos] = make_int2(edge_src[i], dst);
    }
}

__global__ void inv_deg_kernel(const int* __restrict__ deg, float* __restrict__ inv) {
    int i = blockIdx.x * 256 + threadIdx.x;
    if (i < NR * NN) inv[i] = 1.0f / fmaxf((float)deg[i], 1.0f);
}

// ---------------- weight / feature prep ----------------

__global__ void conv_feat_kernel(const float* __restrict__ f, unsigned short* __restrict__ h) {
    int i = (blockIdx.x * 256 + threadIdx.x) * 4;
    if (i < NN * HD) {
        h[i + 0] = f2bf(f[i + 0]);
        h[i + 1] = f2bf(f[i + 1]);
        h[i + 2] = f2bf(f[i + 2]);
        h[i + 3] = f2bf(f[i + 3]);
    }
}

// WtH [128 cols][640 k] bf16: k<128 -> Ws[k][c]; k=128+r*128+kk -> Wr[r][kk][c]
__global__ void prep_wh_kernel(const float* __restrict__ Ws, const float* __restrict__ Wr,
                               unsigned short* __restrict__ Wt) {
    int c = blockIdx.x;     // 128
    int k = threadIdx.x;    // 640
    float v;
    if (k < HD) v = Ws[k * HD + c];
    else {
        int r = (k - HD) >> 7, kk = (k - HD) & 127;
        v = Wr[(r * HD + kk) * HD + c];
    }
    Wt[c * (NR + 1) * HD + k] = f2bf(v);
}

// WtO [128 cols][640 k] bf16: cols >= 100 are zero
__global__ void prep_wo_kernel(const float* __restrict__ Ws, const float* __restrict__ Wr,
                               unsigned short* __restrict__ Wt) {
    int c = blockIdx.x;     // 128
    int k = threadIdx.x;    // 640
    float v = 0.0f;
    if (c < OD) {
        if (k < HD) v = Ws[k * OD + c];
        else {
            int r = (k - HD) >> 7, kk = (k - HD) & 127;
            v = Wr[(r * HD + kk) * OD + c];
        }
    }
    Wt[c * (NR + 1) * HD + k] = f2bf(v);
}

// ---------------- fused: LDS-atomic aggregation + GEMM ----------------
// Block = 32 nodes, 256 threads = 4 waves; wave w = relation w.
// Phase 1: wave walks its contiguous CSR strip, 16 lanes per edge (16B/lane =
//          full 256B h-row per group), 4 edges in flight per round, 3-deep
//          pipelined; fp32 ds_add_f32 accumulation into aggF[32][512]
//          (XOR-swizzled, bank-rotated element order -> ~2-way).
// Phase 2: GEMM [h | inv_deg*aggF](32x640) @ Wt(128x640)^T -> 32x128.
//          A k<128 direct from global h (L2-hot); k>=128 from aggF with
//          inv_deg scale + bf16 convert in-register. B direct from global
//          (Wt 160KB, L2-resident). No barriers in K-loop.
// MODE 0: relu + bf16 out via LDS bounce. MODE 1: f32 out via LDS bounce.

template<int MODE>
__global__ __launch_bounds__(256, 2)
void fused_kernel(const unsigned short* __restrict__ h,
                  const unsigned short* __restrict__ Bt,
                  const int* __restrict__ row_start,
                  const int2* __restrict__ csr_sd,
                  const float* __restrict__ inv_deg,
                  void* __restrict__ outp, int M) {
    __shared__ __align__(16) float aggF[16384];   // [32 rows][512 f32] = 64KB
    const int tid = threadIdx.x;
    const int m0 = blockIdx.x * 32;
    const int lane = tid & 63;
    const int w = tid >> 6;            // wave id = relation

    // ---- zero aggF ----
#pragma unroll
    for (int i = 0; i < 16; i++)
        *(f32x4*)(aggF + (tid + i * 256) * 4) = (f32x4){0.f, 0.f, 0.f, 0.f};
    __syncthreads();

    // ---- gather phase ----
    {
        const int r = w;
        const int nCnt = (M - m0 < 32) ? (M - m0) : 32;
        const int s = row_start[r * (NN + 1) + m0];
        const int e = row_start[r * (NN + 1) + m0 + nCnt];
        const int g = lane >> 4, li = lane & 15;
        const int2* __restrict__ csr = csr_sd + (size_t)r * NE;
        const char* hp = (const char*)h + li * 16;

        const int rounds = (e - s + 3) >> 2;
        int p0 = s + g, p1 = p0 + 4, p2 = p0 + 8;
        int2 sd0, sd1, sd2; int4v v0, v1;
        if (p0 < e) sd0 = csr[p0];
        if (p1 < e) sd1 = csr[p1];
        if (p2 < e) sd2 = csr[p2];
        if (p0 < e) v0 = *(const int4v*)(hp + (size_t)sd0.x * 256);
        if (p1 < e) v1 = *(const int4v*)(hp + (size_t)sd1.x * 256);

        for (int it = 0; it < rounds; ++it) {
            const bool val = p0 < e;
            const int2 sdc = sd0;
            const int4v vc = v0;
            // shift pipeline
            sd0 = sd1; sd1 = sd2; v0 = v1;
            if (p2 + 4 < e) sd2 = csr[p2 + 4];
            if (p2 < e) v1 = *(const int4v*)(hp + (size_t)sd1.x * 256);  // sd1 == old sd2
            if (val) {
                const int row = sdc.y - m0;
                const int xw = (row & 15) << 2;          // word-index XOR
                float* base = aggF + row * 512;
                const unsigned int* vu = (const unsigned int*)&vc;
#pragma unroll
                for (int i = 0; i < 8; i++) {
                    const int i2 = (i + li + 2 * g) & 7; // bank rotation
                    const float f = (i2 & 1) ? bfhi(vu[i2 >> 1]) : bflo(vu[i2 >> 1]);
                    atomicAdd(base + ((r * 128 + li * 8 + i2) ^ xw), f);
                }
            }
            p0 += 4; p1 += 4; p2 += 4;
        }
    }
    __syncthreads();

    // ---- GEMM phase: 4 waves = 4 N-groups of 32 cols; wave tile 32M x 32N ----
    const int lr = lane & 15;
    const int lg = lane >> 4;
    const int wn = w * 32;
    const char* bB = (const char*)Bt;

    int rowg[2]; float invs[2][4];
#pragma unroll
    for (int mi = 0; mi < 2; mi++) {
        int gr = m0 + mi * 16 + lr; if (gr >= M) gr = M - 1;
        rowg[mi] = gr;
#pragma unroll
        for (int rel = 0; rel < 4; rel++)
            invs[mi][rel] = inv_deg[rel * NN + gr];
    }

    f32x4 acc[2][2];
#pragma unroll
    for (int mi = 0; mi < 2; mi++)
#pragma unroll
        for (int ni = 0; ni < 2; ni++) acc[mi][ni] = (f32x4){0.f, 0.f, 0.f, 0.f};

#pragma unroll
    for (int kb = 0; kb < 20; ++kb) {
        bf16x8 af[2], bfr[2];
        if (kb < 4) {
#pragma unroll
            for (int mi = 0; mi < 2; mi++)
                af[mi] = *(const bf16x8*)((const char*)h + (size_t)rowg[mi] * 256 + kb * 64 + lg * 16);
        } else {
            const int rel = (kb - 4) >> 2;
            const int koffw = (kb - 4) * 32 + lg * 8;    // word index in row
#pragma unroll
            for (int mi = 0; mi < 2; mi++) {
                const int row = mi * 16 + lr;
                const int xw = (row & 15) << 2;
                const float* rb = aggF + row * 512;
                const f32x4 fa = *(const f32x4*)(rb + (koffw ^ xw));
                const f32x4 fb = *(const f32x4*)(rb + ((koffw + 4) ^ xw));
                const float sc = invs[mi][rel];
                bf16x8 a;
                a[0] = (short)f2bf(sc * fa[0]); a[1] = (short)f2bf(sc * fa[1]);
                a[2] = (short)f2bf(sc * fa[2]); a[3] = (short)f2bf(sc * fa[3]);
                a[4] = (short)f2bf(sc * fb[0]); a[5] = (short)f2bf(sc * fb[1]);
                a[6] = (short)f2bf(sc * fb[2]); a[7] = (short)f2bf(sc * fb[3]);
                af[mi] = a;
            }
        }
#pragma unroll
        for (int ni = 0; ni < 2; ni++)
            bfr[ni] = *(const bf16x8*)(bB + (size_t)(wn + ni * 16 + lr) * 1280 + kb * 64 + lg * 16);
#pragma unroll
        for (int mi = 0; mi < 2; mi++)
#pragma unroll
            for (int ni = 0; ni < 2; ni++)
                acc[mi][ni] = __builtin_amdgcn_mfma_f32_16x16x32_bf16(af[mi], bfr[ni], acc[mi][ni], 0, 0, 0);
    }

    __syncthreads();                        // everyone done reading aggF
    char* lb = (char*)aggF;                 // reuse LDS as bounce buffer

    if (MODE == 0) {
        // relu -> bf16 tile [32][128] (8KB), then coalesced 16B stores
#pragma unroll
        for (int mi = 0; mi < 2; mi++)
#pragma unroll
            for (int ni = 0; ni < 2; ni++) {
                const int col = wn + ni * 16 + lr;
#pragma unroll
                for (int j = 0; j < 4; j++) {
                    const int row = mi * 16 + lg * 4 + j;
                    *(unsigned short*)(lb + row * 256 + col * 2) =
                        f2bf(fmaxf(acc[mi][ni][j], 0.f));
                }
            }
        __syncthreads();
        unsigned short* o = (unsigned short*)outp;
#pragma unroll
        for (int i = 0; i < 2; i++) {
            const int c = tid + i * 256;       // 512 chunks of 16B
            const int row = c >> 4, o16 = (c & 15) * 16;
            const int grow = m0 + row;
            if (grow < M)
                *(int4v*)((char*)o + (size_t)grow * 256 + o16) = *(const int4v*)(lb + row * 256 + o16);
        }
    } else {
        // f32 tile [32][128] (16KB), then coalesced 16B stores
#pragma unroll
        for (int mi = 0; mi < 2; mi++)
#pragma unroll
            for (int ni = 0; ni < 2; ni++) {
                const int col = wn + ni * 16 + lr;
#pragma unroll
                for (int j = 0; j < 4; j++) {
                    const int row = mi * 16 + lg * 4 + j;
                    *(float*)(lb + row * 512 + col * 4) = acc[mi][ni][j];
                }
            }
        __syncthreads();
        float* o = (float*)outp;
#pragma unroll
        for (int i = 0; i < 4; i++) {
            const int c = tid + i * 256;       // 1024 chunks of 16B
            const int row = c >> 5, o16 = (c & 31) * 16;
            const int grow = m0 + row;
            if (grow < M)
                *(int4v*)((char*)o + (size_t)grow * 512 + o16) = *(const int4v*)(lb + row * 512 + o16);
        }
    }
}

// ---------------- final gather (float4) ----------------

__global__ __launch_bounds__(256) void gather_out_kernel(const float* __restrict__ hOut,
                                                         const int* __restrict__ head,
                                                         const int* __restrict__ tail,
                                                         float* __restrict__ out) {
    const int gid = blockIdx.x * 256 + threadIdx.x;
    const int q = gid >> 5, c = gid & 31;
    if (q >= 2 * NQ || c >= 25) return;
    const int node = (q < NQ) ? head[q] : tail[q - NQ];
    f32x4 v = *(const f32x4*)(hOut + (size_t)node * 128 + c * 4);
    *(f32x4*)(out + (size_t)q * OD + c * 4) = v;
}

// ---------------- launch ----------------

extern "C" void kernel_launch(void* const* d_in, const int* in_sizes, int n_in,
                              void* d_out, int out_size, void* d_ws, size_t ws_size,
                              hipStream_t stream) {
    const float* feature = (const float*)d_in[0];
    const float* Wr_h    = (const float*)d_in[1];   // [2][4][128][128]
    const float* Ws_h    = (const float*)d_in[2];   // [2][128][128]
    const float* Wr_o    = (const float*)d_in[3];   // [4][128][100]
    const float* Ws_o    = (const float*)d_in[4];   // [128][100]
    const int* edge_src  = (const int*)d_in[5];
    const int* edge_dst  = (const int*)d_in[6];
    const int* head_idx  = (const int*)d_in[7];
    const int* tail_idx  = (const int*)d_in[8];
    float* out = (float*)d_out;

    char* ws = (char*)d_ws;
    size_t off = 0;
    auto alloc = [&](size_t bytes) -> void* {
        void* p = ws + off;
        off += (bytes + 255) & ~(size_t)255;
        return p;
    };
    unsigned short* hA   = (unsigned short*)alloc((size_t)NN * HD * 2);
    unsigned short* hB   = (unsigned short*)alloc((size_t)NN * HD * 2);
    float*          hOut = (float*)alloc((size_t)NN * 128 * 4);
    unsigned short* WtH0 = (unsigned short*)alloc(128 * 640 * 2);
    unsigned short* WtH1 = (unsigned short*)alloc(128 * 640 * 2);
    unsigned short* WtO  = (unsigned short*)alloc(128 * 640 * 2);
    int*            deg  = (int*)alloc((size_t)NR * NN * 4);
    float*          inv  = (float*)alloc((size_t)NR * NN * 4);
    int*            rowS = (int*)alloc((size_t)NR * (NN + 1) * 4);
    int*            curs = (int*)alloc((size_t)NR * NN * 4);
    int2*           csrSD= (int2*)alloc((size_t)NR * NE * 8 + 256);
    int*            excl = (int*)alloc((size_t)NR * NN * 4);
    int*            bsum = (int*)alloc((size_t)NR * NB_SCAN * 4);
    (void)ws_size;

    // graph prep
    zero_deg_kernel<<<(NR * NN + 255) / 256, 256, 0, stream>>>(deg);
    count_deg_kernel<<<(NR * NE + 255) / 256, 256, 0, stream>>>(edge_dst, deg);
    scanA_kernel<<<NR * NB_SCAN, 256, 0, stream>>>(deg, excl, bsum);
    scanB_kernel<<<NR, 256, 0, stream>>>(bsum);
    scanC_kernel<<<NR * NB_SCAN, 256, 0, stream>>>(excl, bsum, rowS, curs);
    fill_csr_kernel<<<(NR * NE + 255) / 256, 256, 0, stream>>>(edge_src, edge_dst, curs, csrSD);
    inv_deg_kernel<<<(NR * NN + 255) / 256, 256, 0, stream>>>(deg, inv);

    // weight / feature prep
    conv_feat_kernel<<<(NN * HD / 4 + 255) / 256, 256, 0, stream>>>(feature, hA);
    prep_wh_kernel<<<128, 640, 0, stream>>>(Ws_h, Wr_h, WtH0);
    prep_wh_kernel<<<128, 640, 0, stream>>>(Ws_h + HD * HD, Wr_h + NR * HD * HD, WtH1);
    prep_wo_kernel<<<128, 640, 0, stream>>>(Ws_o, Wr_o, WtO);

    const int fblocks = (NN + 31) / 32;   // 1563

    fused_kernel<0><<<fblocks, 256, 0, stream>>>(hA, WtH0, rowS, csrSD, inv, hB, NN);
    fused_kernel<0><<<fblocks, 256, 0, stream>>>(hB, WtH1, rowS, csrSD, inv, hA, NN);
    fused_kernel<1><<<fblocks, 256, 0, stream>>>(hA, WtO,  rowS, csrSD, inv, hOut, NN);

    gather_out_kernel<<<(2 * NQ * 32 + 255) / 256, 256, 0, stream>>>(hOut, head_idx, tail_idx, out);
}

// Round 6
// 291.140 us; speedup vs baseline: 5.4218x; 5.4218x over previous
//
#include <hip/hip_runtime.h>
#include <hip/hip_bf16.h>

#define NN 50000     // nodes
#define NR 4         // relations
#define NE 160000    // edges per relation
#define HD 128       // hidden dim
#define OD 100       // out dim
#define NQ 8192      // queries
#define NB_SCAN 196  // 196*256 >= NN

typedef __attribute__((ext_vector_type(8))) short bf16x8;
typedef __attribute__((ext_vector_type(4))) float f32x4;
typedef __attribute__((ext_vector_type(4))) int int4v;

static __device__ __forceinline__ unsigned short f2bf(float f) {
    union { float f; unsigned int u; } v; v.f = f;
    unsigned int u = v.u;
    unsigned int r = u + 0x7FFFu + ((u >> 16) & 1u);   // RNE
    return (unsigned short)(r >> 16);
}
static __device__ __forceinline__ float bflo(unsigned int v) {
    union { unsigned int u; float f; } x; x.u = v << 16; return x.f;
}
static __device__ __forceinline__ float bfhi(unsigned int v) {
    union { unsigned int u; float f; } x; x.u = v & 0xffff0000u; return x.f;
}

// ---------------- graph preprocessing ----------------

__global__ void zero_deg_kernel(int* __restrict__ deg) {
    int i = blockIdx.x * 256 + threadIdx.x;
    if (i < NR * NN) deg[i] = 0;
}

__global__ void count_deg_kernel(const int* __restrict__ edge_dst, int* __restrict__ deg) {
    int i = blockIdx.x * 256 + threadIdx.x;
    if (i < NR * NE) {
        int r = i / NE;
        atomicAdd(&deg[r * NN + edge_dst[i]], 1);
    }
}

__global__ __launch_bounds__(256) void scanA_kernel(const int* __restrict__ deg,
                                                    int* __restrict__ excl,
                                                    int* __restrict__ bsum) {
    const int r = blockIdx.x / NB_SCAN;
    const int b = blockIdx.x % NB_SCAN;
    const int tid = threadIdx.x;
    const int idx = b * 256 + tid;
    int v = (idx < NN) ? deg[r * NN + idx] : 0;
    __shared__ int buf[256];
    buf[tid] = v; __syncthreads();
    int sum = v;
    for (int off = 1; off < 256; off <<= 1) {
        int t = (tid >= off) ? buf[tid - off] : 0;
        __syncthreads();
        sum += t; buf[tid] = sum;
        __syncthreads();
    }
    if (idx < NN) excl[r * NN + idx] = sum - v;
    if (tid == 255) bsum[r * NB_SCAN + b] = sum;
}

__global__ __launch_bounds__(256) void scanB_kernel(int* __restrict__ bsum) {
    const int r = blockIdx.x;
    const int tid = threadIdx.x;
    int v = (tid < NB_SCAN) ? bsum[r * NB_SCAN + tid] : 0;
    __shared__ int buf[256];
    buf[tid] = v; __syncthreads();
    int sum = v;
    for (int off = 1; off < 256; off <<= 1) {
        int t = (tid >= off) ? buf[tid - off] : 0;
        __syncthreads();
        sum += t; buf[tid] = sum;
        __syncthreads();
    }
    if (tid < NB_SCAN) bsum[r * NB_SCAN + tid] = sum - v;
}

__global__ __launch_bounds__(256) void scanC_kernel(const int* __restrict__ excl,
                                                    const int* __restrict__ bsum,
                                                    int* __restrict__ row_start,
                                                    int* __restrict__ cursor) {
    const int r = blockIdx.x / NB_SCAN;
    const int b = blockIdx.x % NB_SCAN;
    const int idx = b * 256 + threadIdx.x;
    if (idx < NN) {
        int v = excl[r * NN + idx] + bsum[r * NB_SCAN + b];
        row_start[r * (NN + 1) + idx] = v;
        cursor[r * NN + idx] = v;
    }
    if (b == 0 && threadIdx.x == 0) row_start[r * (NN + 1) + NN] = NE;
}

__global__ void fill_csr_kernel(const int* __restrict__ edge_src,
                                const int* __restrict__ edge_dst,
                                int* __restrict__ cursor, int* __restrict__ csr_src) {
    int i = blockIdx.x * 256 + threadIdx.x;
    if (i < NR * NE) {
        int r = i / NE;
        int dst = edge_dst[i];
        int pos = atomicAdd(&cursor[r * NN + dst], 1);
        csr_src[r * NE + pos] = edge_src[i];
    }
}

__global__ void inv_deg_kernel(const int* __restrict__ deg, float* __restrict__ inv) {
    int i = blockIdx.x * 256 + threadIdx.x;
    if (i < NR * NN) inv[i] = 1.0f / fmaxf((float)deg[i], 1.0f);
}

// ---------------- weight / feature prep ----------------

__global__ void conv_feat_kernel(const float* __restrict__ f, unsigned short* __restrict__ h) {
    int i = (blockIdx.x * 256 + threadIdx.x) * 4;
    if (i < NN * HD) {
        h[i + 0] = f2bf(f[i + 0]);
        h[i + 1] = f2bf(f[i + 1]);
        h[i + 2] = f2bf(f[i + 2]);
        h[i + 3] = f2bf(f[i + 3]);
    }
}

// WtH [128 cols][640 k] bf16: k<128 -> Ws[k][c]; k=128+r*128+kk -> Wr[r][kk][c]
__global__ void prep_wh_kernel(const float* __restrict__ Ws, const float* __restrict__ Wr,
                               unsigned short* __restrict__ Wt) {
    int c = blockIdx.x;     // 128
    int k = threadIdx.x;    // 640
    float v;
    if (k < HD) v = Ws[k * HD + c];
    else {
        int r = (k - HD) >> 7, kk = (k - HD) & 127;
        v = Wr[(r * HD + kk) * HD + c];
    }
    Wt[c * (NR + 1) * HD + k] = f2bf(v);
}

// WtO [128 cols][640 k] bf16: cols >= 100 are zero
__global__ void prep_wo_kernel(const float* __restrict__ Ws, const float* __restrict__ Wr,
                               unsigned short* __restrict__ Wt) {
    int c = blockIdx.x;     // 128
    int k = threadIdx.x;    // 640
    float v = 0.0f;
    if (c < OD) {
        if (k < HD) v = Ws[k * OD + c];
        else {
            int r = (k - HD) >> 7, kk = (k - HD) & 127;
            v = Wr[(r * HD + kk) * OD + c];
        }
    }
    Wt[c * (NR + 1) * HD + k] = f2bf(v);
}

// ---------------- fused: reg-accumulated gather + GEMM ----------------
// Block = 512 thr (8 waves), 32 nodes.
// Phase 0: stage h tile [32][256B] -> LDS (swizzled), 1 x 16B per thread.
// Phase 1: wave w handles nodes 4w..4w+3 sequentially. Within the wave,
//          lane-group g (16 lanes x 16B = full 256B h row) = relation g.
//          Each group walks its CSR segment (avg 3.2 edges) with srcs
//          prefetched 3-deep / values 2-deep; accumulates 8 fp32 in regs;
//          scales by inv_deg; writes one swizzled ds_write_b128 into the
//          agg tile [32][1024B]. No atomics.
// Phase 2: GEMM [hT | agg](32x640) @ Wt(128x640)^T. Wave w owns cols
//          w*16..+16 (B cols read once per block, from L2); A from LDS
//          (XOR swizzle (row&7)<<4); 20 K-steps, no barriers in loop.
// MODE 0: relu + bf16 out via LDS bounce. MODE 1: f32 out via LDS bounce.

template<int MODE>
__global__ __launch_bounds__(512, 2)
void fused_kernel(const unsigned short* __restrict__ h,
                  const unsigned short* __restrict__ Bt,
                  const int* __restrict__ row_start,
                  const int* __restrict__ csr_src,
                  const float* __restrict__ inv_deg,
                  void* __restrict__ outp, int M) {
    __shared__ __align__(16) char lds[40960];   // [0,8192) hT ; [8192,40960) agg
    const int tid = threadIdx.x;
    const int m0 = blockIdx.x * 32;
    const int lane = tid & 63;
    const int w = tid >> 6;            // 0..7

    // ---- phase 0: stage h tile ----
    {
        const int row = tid >> 4, kb = (tid & 15) * 16;
        int gr = m0 + row; if (gr >= M) gr = M - 1;
        int4v v = *(const int4v*)((const char*)h + (size_t)gr * 256 + kb);
        *(int4v*)(lds + row * 256 + (kb ^ ((row & 7) << 4))) = v;
    }

    // ---- phase 1: gather (4 relations in parallel via lane groups) ----
    {
        const int g = lane >> 4, li = lane & 15;
        const int* __restrict__ csr = csr_src + (size_t)g * NE;
        const char* hp = (const char*)h + li * 16;

#pragma unroll
        for (int i = 0; i < 4; ++i) {
            const int n = m0 + (w << 2) + i;
            const bool vn = n < M;
            const int s = vn ? row_start[g * (NN + 1) + n] : 0;
            const int e = vn ? row_start[g * (NN + 1) + n + 1] : 0;

            f32x4 a0 = {0.f, 0.f, 0.f, 0.f}, a1 = {0.f, 0.f, 0.f, 0.f};
            int t = s;
            int sC = 0;
            int4v v0 = {0,0,0,0}, v1 = {0,0,0,0};
            {
                int sA = 0, sB = 0;
                if (t     < e) sA = csr[t];
                if (t + 1 < e) sB = csr[t + 1];
                if (t + 2 < e) sC = csr[t + 2];
                if (t     < e) v0 = *(const int4v*)(hp + (size_t)sA * 256);
                if (t + 1 < e) v1 = *(const int4v*)(hp + (size_t)sB * 256);
            }
            while (__any(t < e)) {
                const bool act = t < e;
                const int4v vc = v0;
                v0 = v1;
                if (t + 2 < e) v1 = *(const int4v*)(hp + (size_t)sC * 256);
                sC = (t + 3 < e) ? csr[t + 3] : 0;
                if (act) {
                    const unsigned int* vu = (const unsigned int*)&vc;
                    a0[0] += bflo(vu[0]); a0[1] += bfhi(vu[0]);
                    a0[2] += bflo(vu[1]); a0[3] += bfhi(vu[1]);
                    a1[0] += bflo(vu[2]); a1[1] += bfhi(vu[2]);
                    a1[2] += bflo(vu[3]); a1[3] += bfhi(vu[3]);
                }
                ++t;
            }
            const float wd = vn ? inv_deg[g * NN + n] : 0.f;
            unsigned int p0 = (unsigned int)f2bf(wd * a0[0]) | ((unsigned int)f2bf(wd * a0[1]) << 16);
            unsigned int p1 = (unsigned int)f2bf(wd * a0[2]) | ((unsigned int)f2bf(wd * a0[3]) << 16);
            unsigned int p2 = (unsigned int)f2bf(wd * a1[0]) | ((unsigned int)f2bf(wd * a1[1]) << 16);
            unsigned int p3 = (unsigned int)f2bf(wd * a1[2]) | ((unsigned int)f2bf(wd * a1[3]) << 16);
            const int row = (w << 2) + i;
            const int cb = g * 256 + li * 16;
            *(int4v*)(lds + 8192 + row * 1024 + (cb ^ ((row & 7) << 4))) =
                (int4v){(int)p0, (int)p1, (int)p2, (int)p3};
        }
    }
    __syncthreads();

    // ---- phase 2: GEMM; wave w owns output cols w*16..w*16+16 ----
    const int lr = lane & 15;
    const int lg = lane >> 4;
    const char* bB = (const char*)Bt + (size_t)(w * 16 + lr) * 1280;

    f32x4 acc[2];
    acc[0] = (f32x4){0.f, 0.f, 0.f, 0.f};
    acc[1] = (f32x4){0.f, 0.f, 0.f, 0.f};

#pragma unroll
    for (int kb = 0; kb < 20; ++kb) {
        const int kByte = kb * 64 + lg * 16;
        bf16x8 bfr = *(const bf16x8*)(bB + kByte);
#pragma unroll
        for (int mi = 0; mi < 2; mi++) {
            const int row = mi * 16 + lr;
            int off;
            if (kb < 4) off = row * 256 + (kByte ^ ((row & 7) << 4));
            else        off = 8192 + row * 1024 + ((kByte - 256) ^ ((row & 7) << 4));
            bf16x8 af = *(const bf16x8*)(lds + off);
            acc[mi] = __builtin_amdgcn_mfma_f32_16x16x32_bf16(af, bfr, acc[mi], 0, 0, 0);
        }
    }

    __syncthreads();                        // all A-reads done; reuse LDS as bounce

    if (MODE == 0) {
        // relu -> bf16 tile [32][256B] at lds[0..8192)
#pragma unroll
        for (int mi = 0; mi < 2; mi++) {
            const int col = w * 16 + lr;
#pragma unroll
            for (int j = 0; j < 4; j++) {
                const int row = mi * 16 + lg * 4 + j;
                *(unsigned short*)(lds + row * 256 + col * 2) =
                    f2bf(fmaxf(acc[mi][j], 0.f));
            }
        }
        __syncthreads();
        unsigned short* o = (unsigned short*)outp;
        const int row = tid >> 4, kb = (tid & 15) * 16;
        const int grow = m0 + row;
        if (grow < M)
            *(int4v*)((char*)o + (size_t)grow * 256 + kb) = *(const int4v*)(lds + row * 256 + kb);
    } else {
        // f32 tile [32][512B] at lds[0..16384)
#pragma unroll
        for (int mi = 0; mi < 2; mi++) {
            const int col = w * 16 + lr;
#pragma unroll
            for (int j = 0; j < 4; j++) {
                const int row = mi * 16 + lg * 4 + j;
                *(float*)(lds + row * 512 + col * 4) = acc[mi][j];
            }
        }
        __syncthreads();
        float* o = (float*)outp;
#pragma unroll
        for (int i = 0; i < 2; i++) {
            const int c = tid + i * 512;       // 1024 chunks of 16B
            const int row = c >> 5, o16 = (c & 31) * 16;
            const int grow = m0 + row;
            if (grow < M)
                *(int4v*)((char*)o + (size_t)grow * 512 + o16) = *(const int4v*)(lds + row * 512 + o16);
        }
    }
}

// ---------------- final gather (float4) ----------------

__global__ __launch_bounds__(256) void gather_out_kernel(const float* __restrict__ hOut,
                                                         const int* __restrict__ head,
                                                         const int* __restrict__ tail,
                                                         float* __restrict__ out) {
    const int gid = blockIdx.x * 256 + threadIdx.x;
    const int q = gid >> 5, c = gid & 31;
    if (q >= 2 * NQ || c >= 25) return;
    const int node = (q < NQ) ? head[q] : tail[q - NQ];
    f32x4 v = *(const f32x4*)(hOut + (size_t)node * 128 + c * 4);
    *(f32x4*)(out + (size_t)q * OD + c * 4) = v;
}

// ---------------- launch ----------------

extern "C" void kernel_launch(void* const* d_in, const int* in_sizes, int n_in,
                              void* d_out, int out_size, void* d_ws, size_t ws_size,
                              hipStream_t stream) {
    const float* feature = (const float*)d_in[0];
    const float* Wr_h    = (const float*)d_in[1];   // [2][4][128][128]
    const float* Ws_h    = (const float*)d_in[2];   // [2][128][128]
    const float* Wr_o    = (const float*)d_in[3];   // [4][128][100]
    const float* Ws_o    = (const float*)d_in[4];   // [128][100]
    const int* edge_src  = (const int*)d_in[5];
    const int* edge_dst  = (const int*)d_in[6];
    const int* head_idx  = (const int*)d_in[7];
    const int* tail_idx  = (const int*)d_in[8];
    float* out = (float*)d_out;

    char* ws = (char*)d_ws;
    size_t off = 0;
    auto alloc = [&](size_t bytes) -> void* {
        void* p = ws + off;
        off += (bytes + 255) & ~(size_t)255;
        return p;
    };
    unsigned short* hA   = (unsigned short*)alloc((size_t)NN * HD * 2);
    unsigned short* hB   = (unsigned short*)alloc((size_t)NN * HD * 2);
    float*          hOut = (float*)alloc((size_t)NN * 128 * 4);
    unsigned short* WtH0 = (unsigned short*)alloc(128 * 640 * 2);
    unsigned short* WtH1 = (unsigned short*)alloc(128 * 640 * 2);
    unsigned short* WtO  = (unsigned short*)alloc(128 * 640 * 2);
    int*            deg  = (int*)alloc((size_t)NR * NN * 4);
    float*          inv  = (float*)alloc((size_t)NR * NN * 4);
    int*            rowS = (int*)alloc((size_t)NR * (NN + 1) * 4);
    int*            curs = (int*)alloc((size_t)NR * NN * 4);
    int*            csrS = (int*)alloc((size_t)NR * NE * 4);
    int*            excl = (int*)alloc((size_t)NR * NN * 4);
    int*            bsum = (int*)alloc((size_t)NR * NB_SCAN * 4);
    (void)ws_size;

    // graph prep
    zero_deg_kernel<<<(NR * NN + 255) / 256, 256, 0, stream>>>(deg);
    count_deg_kernel<<<(NR * NE + 255) / 256, 256, 0, stream>>>(edge_dst, deg);
    scanA_kernel<<<NR * NB_SCAN, 256, 0, stream>>>(deg, excl, bsum);
    scanB_kernel<<<NR, 256, 0, stream>>>(bsum);
    scanC_kernel<<<NR * NB_SCAN, 256, 0, stream>>>(excl, bsum, rowS, curs);
    fill_csr_kernel<<<(NR * NE + 255) / 256, 256, 0, stream>>>(edge_src, edge_dst, curs, csrS);
    inv_deg_kernel<<<(NR * NN + 255) / 256, 256, 0, stream>>>(deg, inv);

    // weight / feature prep
    conv_feat_kernel<<<(NN * HD / 4 + 255) / 256, 256, 0, stream>>>(feature, hA);
    prep_wh_kernel<<<128, 640, 0, stream>>>(Ws_h, Wr_h, WtH0);
    prep_wh_kernel<<<128, 640, 0, stream>>>(Ws_h + HD * HD, Wr_h + NR * HD * HD, WtH1);
    prep_wo_kernel<<<128, 640, 0, stream>>>(Ws_o, Wr_o, WtO);

    const int fblocks = (NN + 31) / 32;   // 1563

    fused_kernel<0><<<fblocks, 512, 0, stream>>>(hA, WtH0, rowS, csrS, inv, hB, NN);
    fused_kernel<0><<<fblocks, 512, 0, stream>>>(hB, WtH1, rowS, csrS, inv, hA, NN);
    fused_kernel<1><<<fblocks, 512, 0, stream>>>(hA, WtO,  rowS, csrS, inv, hOut, NN);

    gather_out_kernel<<<(2 * NQ * 32 + 255) / 256, 256, 0, stream>>>(hOut, head_idx, tail_idx, out);
}